// Round 1
// baseline (1325.940 us; speedup 1.0000x reference)
//
#include <hip/hip_runtime.h>
#include <math.h>

#define NN 20000
#define FDIM 128
#define GM 50
#define GH 16
#define EM 640000
#define EHULL 200000

__device__ __forceinline__ float ssp_f(float x) {
    // softplus(x) - log(2), numerically stable, fast intrinsics (err ~1e-6 abs)
    float ax = fabsf(x);
    return fmaxf(x, 0.0f) + __logf(1.0f + __expf(-ax)) - 0.69314718055994531f;
}

// dst[c*R + r] = src[r*C + c]   (small weight transposes, run once per call)
__global__ void transpose_k(const float* __restrict__ src, float* __restrict__ dst,
                            int R, int C) {
    int i = blockIdx.x * blockDim.x + threadIdx.x;
    if (i < R * C) {
        int r = i / C, c = i % C;
        dst[c * R + r] = src[i];
    }
}

// v_ = v @ lin_w^T and v_hull = v @ lin_hull_w^T, 64 nodes per block.
__global__ __launch_bounds__(256) void lin_k(const float* __restrict__ v,
                                             const float* __restrict__ linT,   // [128][128] (h-major)
                                             const float* __restrict__ linHT,  // [128][128]
                                             float* __restrict__ v_out,
                                             float* __restrict__ v_hull_out) {
    __shared__ __align__(16) float wT_s[128 * 128];  // [h][f]
    __shared__ __align__(16) float vT_s[128 * 68];   // [h][n] padded rows (272B)
    const int t = threadIdx.x;
    const int node0 = blockIdx.x * 64;

    // stage v tile transposed: vT_s[h][n]
    for (int i = t; i < 64 * 128; i += 256) {
        int n = i >> 7, h = i & 127;
        float val = 0.0f;
        if (node0 + n < NN) val = v[(node0 + n) * 128 + h];
        vT_s[h * 68 + n] = val;
    }

    const float* wsrc[2] = {linT, linHT};
    float* dsts[2] = {v_out, v_hull_out};

    const int l = t & 31;
    const int f0 = l * 4;
    const int n0 = (t >> 5) * 8;

#pragma unroll
    for (int w = 0; w < 2; ++w) {
        __syncthreads();
        for (int i = t * 4; i < 128 * 128; i += 256 * 4)
            *(float4*)&wT_s[i] = *(const float4*)&wsrc[w][i];
        __syncthreads();

        float acc[8][4];
#pragma unroll
        for (int ni = 0; ni < 8; ++ni)
#pragma unroll
            for (int fi = 0; fi < 4; ++fi) acc[ni][fi] = 0.0f;

        for (int h = 0; h < 128; ++h) {
            float4 w4 = *(float4*)&wT_s[h * 128 + f0];
            float4 a4 = *(float4*)&vT_s[h * 68 + n0];
            float4 b4 = *(float4*)&vT_s[h * 68 + n0 + 4];
            float av[8] = {a4.x, a4.y, a4.z, a4.w, b4.x, b4.y, b4.z, b4.w};
#pragma unroll
            for (int ni = 0; ni < 8; ++ni) {
                acc[ni][0] = fmaf(av[ni], w4.x, acc[ni][0]);
                acc[ni][1] = fmaf(av[ni], w4.y, acc[ni][1]);
                acc[ni][2] = fmaf(av[ni], w4.z, acc[ni][2]);
                acc[ni][3] = fmaf(av[ni], w4.w, acc[ni][3]);
            }
        }
#pragma unroll
        for (int ni = 0; ni < 8; ++ni) {
            int n = node0 + n0 + ni;
            if (n < NN) {
                float4 o = {acc[ni][0], acc[ni][1], acc[ni][2], acc[ni][3]};
                *(float4*)&dsts[w][n * 128 + f0] = o;
            }
        }
    }
}

// Fused per-edge: W = (ssp(emb @ W1^T + b1) @ W2^T + b2) [* C]; out = vsrc[j] * W
// 64 edges per block, 512 threads, weights LDS-stationary.
template <int G, bool ENV>
__global__ __launch_bounds__(512) void edge_k(const float* __restrict__ emb,   // [E][G]
                                              const float* __restrict__ dist,  // [E]
                                              const int* __restrict__ jidx,    // [E]
                                              const float* __restrict__ W1T,   // [G][128]
                                              const float* __restrict__ W2T,   // [128][128]
                                              const float* __restrict__ b1,
                                              const float* __restrict__ b2,
                                              const float* __restrict__ vsrc,  // [N][128]
                                              float* __restrict__ out) {
    __shared__ __align__(16) float W1T_s[G * 128];    // [g][f]
    __shared__ __align__(16) float W2T_s[128 * 128];  // [k][f]
    __shared__ __align__(16) float embT_s[G * 64];    // [g][ed]
    __shared__ __align__(16) float hT_s[128 * 68];    // [k][ed] padded rows

    const int t = threadIdx.x;
    const int e0 = blockIdx.x * 64;

    for (int i = t * 4; i < G * 128; i += 512 * 4)
        *(float4*)&W1T_s[i] = *(const float4*)&W1T[i];
    for (int i = t * 4; i < 128 * 128; i += 512 * 4)
        *(float4*)&W2T_s[i] = *(const float4*)&W2T[i];
    for (int i = t; i < G * 64; i += 512) {
        int ed = i / G, g = i % G;
        embT_s[g * 64 + ed] = emb[(e0 + ed) * G + g];
    }
    __syncthreads();

    const int l = t & 31;
    const int ed0 = (t >> 5) * 4;

    // ---- layer 1: hT[f][ed] = ssp(emb @ W1^T + b1), f strided by 32 per thread
    {
        float acc1[4][4];  // [fi][ei]
#pragma unroll
        for (int fi = 0; fi < 4; ++fi)
#pragma unroll
            for (int ei = 0; ei < 4; ++ei) acc1[fi][ei] = 0.0f;

        for (int g = 0; g < G; ++g) {
            float4 d4 = *(float4*)&embT_s[g * 64 + ed0];
#pragma unroll
            for (int fi = 0; fi < 4; ++fi) {
                float w = W1T_s[g * 128 + l + fi * 32];
                acc1[fi][0] = fmaf(w, d4.x, acc1[fi][0]);
                acc1[fi][1] = fmaf(w, d4.y, acc1[fi][1]);
                acc1[fi][2] = fmaf(w, d4.z, acc1[fi][2]);
                acc1[fi][3] = fmaf(w, d4.w, acc1[fi][3]);
            }
        }
#pragma unroll
        for (int fi = 0; fi < 4; ++fi) {
            int f = l + fi * 32;
            float bb = b1[f];
            float4 hv;
            hv.x = ssp_f(acc1[fi][0] + bb);
            hv.y = ssp_f(acc1[fi][1] + bb);
            hv.z = ssp_f(acc1[fi][2] + bb);
            hv.w = ssp_f(acc1[fi][3] + bb);
            *(float4*)&hT_s[f * 68 + ed0] = hv;
        }
    }
    __syncthreads();

    // ---- layer 2: acc2[ei][fi] = h @ W2^T, f contiguous per thread
    const int f0 = l * 4;
    float acc2[4][4];
#pragma unroll
    for (int ei = 0; ei < 4; ++ei)
#pragma unroll
        for (int fi = 0; fi < 4; ++fi) acc2[ei][fi] = 0.0f;

#pragma unroll 8
    for (int k = 0; k < 128; ++k) {
        float4 h4 = *(float4*)&hT_s[k * 68 + ed0];
        float4 w4 = *(float4*)&W2T_s[k * 128 + f0];
        acc2[0][0] = fmaf(h4.x, w4.x, acc2[0][0]);
        acc2[0][1] = fmaf(h4.x, w4.y, acc2[0][1]);
        acc2[0][2] = fmaf(h4.x, w4.z, acc2[0][2]);
        acc2[0][3] = fmaf(h4.x, w4.w, acc2[0][3]);
        acc2[1][0] = fmaf(h4.y, w4.x, acc2[1][0]);
        acc2[1][1] = fmaf(h4.y, w4.y, acc2[1][1]);
        acc2[1][2] = fmaf(h4.y, w4.z, acc2[1][2]);
        acc2[1][3] = fmaf(h4.y, w4.w, acc2[1][3]);
        acc2[2][0] = fmaf(h4.z, w4.x, acc2[2][0]);
        acc2[2][1] = fmaf(h4.z, w4.y, acc2[2][1]);
        acc2[2][2] = fmaf(h4.z, w4.z, acc2[2][2]);
        acc2[2][3] = fmaf(h4.z, w4.w, acc2[2][3]);
        acc2[3][0] = fmaf(h4.w, w4.x, acc2[3][0]);
        acc2[3][1] = fmaf(h4.w, w4.y, acc2[3][1]);
        acc2[3][2] = fmaf(h4.w, w4.z, acc2[3][2]);
        acc2[3][3] = fmaf(h4.w, w4.w, acc2[3][3]);
    }

    float4 b2v = *(const float4*)&b2[f0];
#pragma unroll
    for (int ei = 0; ei < 4; ++ei) {
        int edge = e0 + ed0 + ei;
        int j = jidx[edge];
        float scale = 1.0f;
        if (ENV) scale = 0.5f * __cosf(dist[edge] * 0.31415926535897932f) + 0.5f;
        float4 vv = *(const float4*)&vsrc[j * 128 + f0];
        float4 o;
        o.x = (acc2[ei][0] + b2v.x) * scale * vv.x;
        o.y = (acc2[ei][1] + b2v.y) * scale * vv.y;
        o.z = (acc2[ei][2] + b2v.z) * scale * vv.z;
        o.w = (acc2[ei][3] + b2v.w) * scale * vv.w;
        *(float4*)&out[edge * 128 + f0] = o;
    }
}

extern "C" void kernel_launch(void* const* d_in, const int* in_sizes, int n_in,
                              void* d_out, int out_size, void* d_ws, size_t ws_size,
                              hipStream_t stream) {
    const float* v          = (const float*)d_in[0];
    const float* dist       = (const float*)d_in[1];
    const float* dist_emb   = (const float*)d_in[2];
    const float* fea_hull   = (const float*)d_in[3];
    const int*   eidx       = (const int*)d_in[4];   // row 0 = j
    const int*   eidx_h     = (const int*)d_in[5];
    const float* lin_w      = (const float*)d_in[6];
    const float* mlp1_w     = (const float*)d_in[7];
    const float* mlp1_b     = (const float*)d_in[8];
    const float* mlp2_w     = (const float*)d_in[9];
    const float* mlp2_b     = (const float*)d_in[10];
    const float* lin_hull_w = (const float*)d_in[11];
    const float* mlph1_w    = (const float*)d_in[12];
    const float* mlph1_b    = (const float*)d_in[13];
    const float* mlph2_w    = (const float*)d_in[14];
    const float* mlph2_b    = (const float*)d_in[15];

    float* ws     = (float*)d_ws;
    float* v_     = ws;                       // 20000*128
    float* v_hull = v_ + NN * FDIM;           // 20000*128
    float* linT   = v_hull + NN * FDIM;       // 128*128
    float* linHT  = linT + FDIM * FDIM;
    float* W1T    = linHT + FDIM * FDIM;      // 50*128
    float* W2T    = W1T + GM * FDIM;          // 128*128
    float* Wh1T   = W2T + FDIM * FDIM;        // 16*128
    float* Wh2T   = Wh1T + GH * FDIM;         // 128*128
    // total ws use: ~20.75 MB

    transpose_k<<<(FDIM * FDIM + 255) / 256, 256, 0, stream>>>(lin_w, linT, FDIM, FDIM);
    transpose_k<<<(FDIM * FDIM + 255) / 256, 256, 0, stream>>>(lin_hull_w, linHT, FDIM, FDIM);
    transpose_k<<<(FDIM * GM + 255) / 256, 256, 0, stream>>>(mlp1_w, W1T, FDIM, GM);
    transpose_k<<<(FDIM * FDIM + 255) / 256, 256, 0, stream>>>(mlp2_w, W2T, FDIM, FDIM);
    transpose_k<<<(FDIM * GH + 255) / 256, 256, 0, stream>>>(mlph1_w, Wh1T, FDIM, GH);
    transpose_k<<<(FDIM * FDIM + 255) / 256, 256, 0, stream>>>(mlph2_w, Wh2T, FDIM, FDIM);

    lin_k<<<(NN + 63) / 64, 256, 0, stream>>>(v, linT, linHT, v_, v_hull);

    float* out = (float*)d_out;
    edge_k<GM, true><<<EM / 64, 512, 0, stream>>>(dist_emb, dist, eidx, W1T, W2T,
                                                  mlp1_b, mlp2_b, v_, out);
    edge_k<GH, false><<<EHULL / 64, 512, 0, stream>>>(fea_hull, nullptr, eidx_h, Wh1T, Wh2T,
                                                      mlph1_b, mlph2_b, v_hull,
                                                      out + (long)EM * FDIM);
}

// Round 2
// 996.199 us; speedup vs baseline: 1.3310x; 1.3310x over previous
//
#include <hip/hip_runtime.h>
#include <math.h>

#define NN 20000
#define FDIM 128
#define EM 640000
#define EHULL 200000

typedef _Float16 hv2 __attribute__((ext_vector_type(2)));
typedef _Float16 hv4 __attribute__((ext_vector_type(4)));
typedef _Float16 hv8 __attribute__((ext_vector_type(8)));
typedef float f32x4 __attribute__((ext_vector_type(4)));

__device__ __forceinline__ float ssp_f(float x) {
    float ax = fabsf(x);
    return fmaxf(x, 0.0f) + __logf(1.0f + __expf(-ax)) - 0.69314718055994531f;
}

// swizzled byte offset: row-major [row][colb bytes], XOR 16B-chunk swizzle
__device__ __forceinline__ int swz(int row, int colb, int rb, int mask) {
    return row * rb + (colb ^ ((row & mask) << 4));
}

// ---------------------------------------------------------------------------
// Fused edge MLP: out[e][f] = (ssp(emb[e]@W1^T + b1) @ W2^T + b2)[*C(dist)] * vsrc[j[e]]
// 128 edges / block, 512 threads (8 waves x 16-edge tiles), fp16 MFMA.
// Layer 1 computed swapped (h^T = W1 @ emb^T) so D-regs pack 4 consecutive f
// per lane -> 8B ds_write into h[e][k], which is layer-2's A layout.
// ---------------------------------------------------------------------------
template <int GDIM, int GPAD, bool ENV>
__global__ __launch_bounds__(512) void edge_mfma(
        const float* __restrict__ emb, const float* __restrict__ dist,
        const int* __restrict__ jidx, const float* __restrict__ W1,
        const float* __restrict__ b1, const float* __restrict__ W2,
        const float* __restrict__ b2, const float* __restrict__ vsrc,
        float* __restrict__ out, int E) {
    constexpr int RB1 = GPAD * 2;                // row bytes of [.][GPAD] fp16 tiles
    constexpr int M1 = (RB1 >= 128) ? 7 : 3;     // swizzle mask
    constexpr int NK1 = GPAD / 32;               // K-chunks in layer 1
    constexpr int GP2 = GPAD / 2;

    __shared__ __align__(16) _Float16 W1s[128 * GPAD];   // [f][g]
    __shared__ __align__(16) _Float16 W2s[128 * 128];    // [f][k]
    __shared__ __align__(16) _Float16 embs[128 * GPAD];  // [e][g]
    __shared__ __align__(16) _Float16 hs[128 * 128];     // [e][k]

    const int t = threadIdx.x;
    const int e0 = blockIdx.x * 128;

    // ---- stage W2 [128][128] f32 -> fp16 swizzled
    for (int i = t; i < 128 * 32; i += 512) {
        int r = i >> 5, c = i & 31;
        float4 x = *(const float4*)&W2[r * 128 + c * 4];
        hv4 h = {(_Float16)x.x, (_Float16)x.y, (_Float16)x.z, (_Float16)x.w};
        *(hv4*)((char*)W2s + swz(r, c * 8, 256, 7)) = h;
    }
    // ---- stage W1 [128][GDIM] -> [128][GPAD] (zero-pad g)
    for (int i = t; i < 128 * GP2; i += 512) {
        int r = i / GP2, gp = i % GP2;
        float2 x = make_float2(0.f, 0.f);
        if (gp * 2 < GDIM) x = *(const float2*)&W1[r * GDIM + gp * 2];
        hv2 h = {(_Float16)x.x, (_Float16)x.y};
        *(hv2*)((char*)W1s + swz(r, gp * 4, RB1, M1)) = h;
    }
    // ---- stage emb tile [128][GDIM] -> [128][GPAD]
    for (int i = t; i < 128 * GP2; i += 512) {
        int e = i / GP2, gp = i % GP2;
        float2 x = make_float2(0.f, 0.f);
        if (gp * 2 < GDIM && e0 + e < E) x = *(const float2*)&emb[(e0 + e) * GDIM + gp * 2];
        hv2 h = {(_Float16)x.x, (_Float16)x.y};
        *(hv2*)((char*)embs + swz(e, gp * 4, RB1, M1)) = h;
    }
    __syncthreads();

    const int w = t >> 6, l = t & 63, li = l & 15, lg = l >> 4;

    // ---- layer 1: D[f][e] = W1 @ emb^T  (wave w owns edges w*16..w*16+15)
    hv8 bfrag[NK1];
#pragma unroll
    for (int kk = 0; kk < NK1; ++kk)
        bfrag[kk] = *(const hv8*)((const char*)embs +
                                  swz(w * 16 + li, kk * 64 + lg * 16, RB1, M1));
#pragma unroll
    for (int ft = 0; ft < 8; ++ft) {
        f32x4 acc = {0.f, 0.f, 0.f, 0.f};
#pragma unroll
        for (int kk = 0; kk < NK1; ++kk) {
            hv8 af = *(const hv8*)((const char*)W1s +
                                   swz(ft * 16 + li, kk * 64 + lg * 16, RB1, M1));
            acc = __builtin_amdgcn_mfma_f32_16x16x32_f16(af, bfrag[kk], acc, 0, 0, 0);
        }
        // lane holds rows f = ft*16 + lg*4 + r, col e = w*16 + li
        float4 bb = *(const float4*)&b1[ft * 16 + lg * 4];
        hv4 hh;
        hh[0] = (_Float16)ssp_f(acc[0] + bb.x);
        hh[1] = (_Float16)ssp_f(acc[1] + bb.y);
        hh[2] = (_Float16)ssp_f(acc[2] + bb.z);
        hh[3] = (_Float16)ssp_f(acc[3] + bb.w);
        *(hv4*)((char*)hs + swz(w * 16 + li, ft * 32 + lg * 8, 256, 7)) = hh;
    }
    __syncthreads();

    // ---- layer 2: out[e][f] = h @ W2^T
    hv8 afrag[4];
#pragma unroll
    for (int kk = 0; kk < 4; ++kk)
        afrag[kk] = *(const hv8*)((const char*)hs +
                                  swz(w * 16 + li, kk * 64 + lg * 16, 256, 7));

    const int ebase = e0 + w * 16 + lg * 4;
    int j4[4];
    float c4[4] = {1.f, 1.f, 1.f, 1.f};
#pragma unroll
    for (int r = 0; r < 4; ++r) {
        int ed = ebase + r;
        bool ok = ed < E;
        j4[r] = ok ? jidx[ed] : 0;
        if (ENV) {
            float dd = ok ? dist[ed] : 0.f;
            c4[r] = 0.5f * __cosf(dd * 0.31415926535897932f) + 0.5f;
        }
    }

#pragma unroll
    for (int nt = 0; nt < 8; ++nt) {
        f32x4 acc = {0.f, 0.f, 0.f, 0.f};
#pragma unroll
        for (int kk = 0; kk < 4; ++kk) {
            hv8 bf = *(const hv8*)((const char*)W2s +
                                   swz(nt * 16 + li, kk * 64 + lg * 16, 256, 7));
            acc = __builtin_amdgcn_mfma_f32_16x16x32_f16(afrag[kk], bf, acc, 0, 0, 0);
        }
        // lane holds rows e = ebase + r, col f = nt*16 + li
        int f = nt * 16 + li;
        float b2v = b2[f];
#pragma unroll
        for (int r = 0; r < 4; ++r) {
            int ed = ebase + r;
            if (ed < E) {
                float res = (acc[r] + b2v) * vsrc[j4[r] * 128 + f];
                if (ENV) res *= c4[r];
                out[ed * 128 + f] = res;
            }
        }
    }
}

// ---------------------------------------------------------------------------
// v_ = v @ lin_w^T and v_hull = v @ lin_hull_w^T.  128 nodes / block, fp16 MFMA.
// ---------------------------------------------------------------------------
__global__ __launch_bounds__(512) void lin_mfma(
        const float* __restrict__ v, const float* __restrict__ wA,
        const float* __restrict__ wB, float* __restrict__ oA,
        float* __restrict__ oB) {
    __shared__ __align__(16) _Float16 vs[128 * 128];   // [n][h]
    __shared__ __align__(16) _Float16 wAs[128 * 128];  // [f][h]
    __shared__ __align__(16) _Float16 wBs[128 * 128];

    const int t = threadIdx.x;
    const int n0 = blockIdx.x * 128;

    for (int i = t; i < 128 * 32; i += 512) {
        int r = i >> 5, c = i & 31;
        float4 xa = *(const float4*)&wA[r * 128 + c * 4];
        hv4 ha = {(_Float16)xa.x, (_Float16)xa.y, (_Float16)xa.z, (_Float16)xa.w};
        *(hv4*)((char*)wAs + swz(r, c * 8, 256, 7)) = ha;
        float4 xb = *(const float4*)&wB[r * 128 + c * 4];
        hv4 hb = {(_Float16)xb.x, (_Float16)xb.y, (_Float16)xb.z, (_Float16)xb.w};
        *(hv4*)((char*)wBs + swz(r, c * 8, 256, 7)) = hb;
        float4 xv = make_float4(0.f, 0.f, 0.f, 0.f);
        if (n0 + r < NN) xv = *(const float4*)&v[(n0 + r) * 128 + c * 4];
        hv4 hx = {(_Float16)xv.x, (_Float16)xv.y, (_Float16)xv.z, (_Float16)xv.w};
        *(hv4*)((char*)vs + swz(r, c * 8, 256, 7)) = hx;
    }
    __syncthreads();

    const int w = t >> 6, l = t & 63, li = l & 15, lg = l >> 4;

    hv8 afrag[4];
#pragma unroll
    for (int kk = 0; kk < 4; ++kk)
        afrag[kk] = *(const hv8*)((const char*)vs +
                                  swz(w * 16 + li, kk * 64 + lg * 16, 256, 7));

#pragma unroll
    for (int sel = 0; sel < 2; ++sel) {
        const _Float16* wsel = sel ? wBs : wAs;
        float* osel = sel ? oB : oA;
#pragma unroll
        for (int nt = 0; nt < 8; ++nt) {
            f32x4 acc = {0.f, 0.f, 0.f, 0.f};
#pragma unroll
            for (int kk = 0; kk < 4; ++kk) {
                hv8 bf = *(const hv8*)((const char*)wsel +
                                       swz(nt * 16 + li, kk * 64 + lg * 16, 256, 7));
                acc = __builtin_amdgcn_mfma_f32_16x16x32_f16(afrag[kk], bf, acc, 0, 0, 0);
            }
            int f = nt * 16 + li;
#pragma unroll
            for (int r = 0; r < 4; ++r) {
                int n = n0 + w * 16 + lg * 4 + r;
                if (n < NN) osel[n * 128 + f] = acc[r];
            }
        }
    }
}

extern "C" void kernel_launch(void* const* d_in, const int* in_sizes, int n_in,
                              void* d_out, int out_size, void* d_ws, size_t ws_size,
                              hipStream_t stream) {
    const float* v          = (const float*)d_in[0];
    const float* dist       = (const float*)d_in[1];
    const float* dist_emb   = (const float*)d_in[2];
    const float* fea_hull   = (const float*)d_in[3];
    const int*   eidx       = (const int*)d_in[4];   // row 0 = j
    const int*   eidx_h     = (const int*)d_in[5];
    const float* lin_w      = (const float*)d_in[6];
    const float* mlp1_w     = (const float*)d_in[7];
    const float* mlp1_b     = (const float*)d_in[8];
    const float* mlp2_w     = (const float*)d_in[9];
    const float* mlp2_b     = (const float*)d_in[10];
    const float* lin_hull_w = (const float*)d_in[11];
    const float* mlph1_w    = (const float*)d_in[12];
    const float* mlph1_b    = (const float*)d_in[13];
    const float* mlph2_w    = (const float*)d_in[14];
    const float* mlph2_b    = (const float*)d_in[15];

    float* ws     = (float*)d_ws;
    float* v_     = ws;                 // 20000*128 f32
    float* v_hull = v_ + NN * FDIM;     // 20000*128 f32

    lin_mfma<<<(NN + 127) / 128, 512, 0, stream>>>(v, lin_w, lin_hull_w, v_, v_hull);

    float* out = (float*)d_out;
    edge_mfma<50, 64, true><<<(EM + 127) / 128, 512, 0, stream>>>(
        dist_emb, dist, eidx, mlp1_w, mlp1_b, mlp2_w, mlp2_b, v_, out, EM);
    edge_mfma<16, 32, false><<<(EHULL + 127) / 128, 512, 0, stream>>>(
        fea_hull, nullptr, eidx_h, mlph1_w, mlph1_b, mlph2_w, mlph2_b, v_hull,
        out + (long)EM * FDIM, EHULL);
}

// Round 3
// 786.930 us; speedup vs baseline: 1.6850x; 1.2659x over previous
//
#include <hip/hip_runtime.h>
#include <math.h>

#define NN 20000
#define FDIM 128
#define EM 640000
#define EHULL 200000
#define MAIN_BLOCKS (EM / 64)    // 10000
#define HULL_BLOCKS (EHULL / 64) // 3125

typedef _Float16 hv2 __attribute__((ext_vector_type(2)));
typedef _Float16 hv4 __attribute__((ext_vector_type(4)));
typedef _Float16 hv8 __attribute__((ext_vector_type(8)));
typedef float f32x4 __attribute__((ext_vector_type(4)));

// fp16 fragment regions inside d_ws (element offsets, after 2 f32 node arrays)
#define OFF_W1F 0               // 16 fb  (mlp1_w,  C=50,  NK=2)
#define OFF_W2F 8192            // 32 fb  (mlp2_w,  C=128, NK=4)
#define OFF_WH1F 24576          // 8 fb   (mlph1_w, C=16,  NK=1)
#define OFF_WH2F 28672          // 32 fb  (mlph2_w, C=128, NK=4)
#define OFF_LAF 45056           // 32 fb  (lin_w,   C=128, NK=4)
#define OFF_LBF 61440           // 32 fb  (lin_hull_w)
#define FRAG_TOTAL 77824        // fp16 elements

__device__ __forceinline__ float ssp_f(float x) {
    float ax = fabsf(x);
    return fmaxf(x, 0.0f) + __logf(1.0f + __expf(-ax)) - 0.69314718055994531f;
}

// swizzled byte offset: row-major [row][rb bytes], XOR 16B-chunk swizzle
__device__ __forceinline__ int swz(int row, int colb, int rb) {
    return row * rb + (colb ^ ((row & 7) << 4));
}

__device__ __forceinline__ float2 ntload2(const float* p) {
    unsigned long long u = __builtin_nontemporal_load((const unsigned long long*)p);
    float2 r;
    __builtin_memcpy(&r, &u, 8);
    return r;
}

// ---------------------------------------------------------------------------
// Convert all weights to fp16 MFMA-fragment order:
//   dst[fb*512 + l*8 + j] = W[f*C + g], f = nt*16 + (l&15), g = kk*32 + (l>>4)*8 + j
// (identical layout serves A-frags (rows f, k=g) and B-frags (cols f, k=g))
// ---------------------------------------------------------------------------
__global__ __launch_bounds__(256) void prep_k(
        const float* __restrict__ mlp1_w, const float* __restrict__ mlp2_w,
        const float* __restrict__ mlph1_w, const float* __restrict__ mlph2_w,
        const float* __restrict__ lin_w, const float* __restrict__ lin_hull_w,
        _Float16* __restrict__ dst) {
    int i = blockIdx.x * 256 + threadIdx.x;
    if (i >= FRAG_TOTAL) return;
    int fbi = i >> 9, within = i & 511;
    int l = within >> 3, j = within & 7;
    const float* src;
    int C, NK, base;
    if (fbi < 16)       { src = mlp1_w;     C = 50;  NK = 2; base = 0; }
    else if (fbi < 48)  { src = mlp2_w;     C = 128; NK = 4; base = 16; }
    else if (fbi < 56)  { src = mlph1_w;    C = 16;  NK = 1; base = 48; }
    else if (fbi < 88)  { src = mlph2_w;    C = 128; NK = 4; base = 56; }
    else if (fbi < 120) { src = lin_w;      C = 128; NK = 4; base = 88; }
    else                { src = lin_hull_w; C = 128; NK = 4; base = 120; }
    int local = fbi - base;
    int nt = local / NK, kk = local % NK;
    int f = nt * 16 + (l & 15);
    int g = kk * 32 + (l >> 4) * 8 + j;
    float val = (g < C) ? src[f * C + g] : 0.0f;
    dst[i] = (_Float16)val;
}

// ---------------------------------------------------------------------------
// v_ = v @ lin_w^T and v_hull = v @ lin_hull_w^T; B-frags from global.
// ---------------------------------------------------------------------------
__global__ __launch_bounds__(512) void lin_mfma(
        const float* __restrict__ v, const hv8* __restrict__ LAf,
        const hv8* __restrict__ LBf, float* __restrict__ oA,
        float* __restrict__ oB) {
    __shared__ __align__(16) _Float16 vs[128 * 128];  // [n][h] swizzled, 32KB
    const int t = threadIdx.x;
    const int n0 = blockIdx.x * 128;

    for (int i = t; i < 128 * 32; i += 512) {
        int r = i >> 5, c = i & 31;
        float4 x = make_float4(0.f, 0.f, 0.f, 0.f);
        if (n0 + r < NN) x = *(const float4*)&v[(n0 + r) * 128 + c * 4];
        hv4 h = {(_Float16)x.x, (_Float16)x.y, (_Float16)x.z, (_Float16)x.w};
        *(hv4*)((char*)vs + swz(r, c * 8, 256)) = h;
    }
    __syncthreads();

    const int w = t >> 6, l = t & 63, li = l & 15, lg = l >> 4;

    hv8 afrag[4];
#pragma unroll
    for (int kk = 0; kk < 4; ++kk)
        afrag[kk] = *(const hv8*)((const char*)vs + swz(w * 16 + li, kk * 64 + lg * 16, 256));

#pragma unroll
    for (int sel = 0; sel < 2; ++sel) {
        const hv8* B = sel ? LBf : LAf;
        float* o = sel ? oB : oA;
#pragma unroll
        for (int nt = 0; nt < 8; ++nt) {
            f32x4 acc = {0.f, 0.f, 0.f, 0.f};
#pragma unroll
            for (int kk = 0; kk < 4; ++kk)
                acc = __builtin_amdgcn_mfma_f32_16x16x32_f16(afrag[kk], B[(nt * 4 + kk) * 64 + l],
                                                             acc, 0, 0, 0);
            int f = nt * 16 + li;
#pragma unroll
            for (int r = 0; r < 4; ++r) {
                int n = n0 + w * 16 + lg * 4 + r;
                if (n < NN) o[n * 128 + f] = acc[r];
            }
        }
    }
}

// ---------------------------------------------------------------------------
// Fused edge MLP, 64 edges / 256 threads (4 waves x 16 edges).
// Weights come as global fp16 fragments (L1/L2-hot); LDS only for emb + h.
// ---------------------------------------------------------------------------
template <int GDIM, int GPAD, bool ENV>
__device__ __forceinline__ void edge_body(
        int bid, const float* __restrict__ emb, const float* __restrict__ dist,
        const int* __restrict__ jidx, const hv8* __restrict__ W1f,
        const float* __restrict__ b1, const hv8* __restrict__ W2f,
        const float* __restrict__ b2, const float* __restrict__ vsrc,
        float* __restrict__ out, _Float16* embs /*[64*64] rows 128B*/,
        _Float16* hs /*[64*128] rows 256B*/) {
    constexpr int NK1 = GPAD / 32;
    constexpr int GP2 = GPAD / 2;

    const int t = threadIdx.x;
    const int e0 = bid * 64;

    // stage emb tile -> fp16 swizzled LDS (rows padded to 128B)
    for (int i = t; i < 64 * GP2; i += 256) {
        int e = i / GP2, gp = i % GP2;
        float2 x = make_float2(0.f, 0.f);
        if (gp * 2 < GDIM) x = ntload2(&emb[(long)(e0 + e) * GDIM + gp * 2]);
        hv2 h = {(_Float16)x.x, (_Float16)x.y};
        *(hv2*)((char*)embs + swz(e, gp * 4, 128)) = h;
    }
    __syncthreads();

    const int w = t >> 6, l = t & 63, li = l & 15, lg = l >> 4;

    // ---- layer 1 (swapped): D[f][e] = W1 @ emb^T
    hv8 bfrag[NK1];
#pragma unroll
    for (int kk = 0; kk < NK1; ++kk)
        bfrag[kk] = *(const hv8*)((const char*)embs + swz(w * 16 + li, kk * 64 + lg * 16, 128));
#pragma unroll
    for (int ft = 0; ft < 8; ++ft) {
        f32x4 acc = {0.f, 0.f, 0.f, 0.f};
#pragma unroll
        for (int kk = 0; kk < NK1; ++kk)
            acc = __builtin_amdgcn_mfma_f32_16x16x32_f16(W1f[(ft * NK1 + kk) * 64 + l],
                                                         bfrag[kk], acc, 0, 0, 0);
        float4 bb = *(const float4*)&b1[ft * 16 + lg * 4];
        hv4 hh;
        hh[0] = (_Float16)ssp_f(acc[0] + bb.x);
        hh[1] = (_Float16)ssp_f(acc[1] + bb.y);
        hh[2] = (_Float16)ssp_f(acc[2] + bb.z);
        hh[3] = (_Float16)ssp_f(acc[3] + bb.w);
        *(hv4*)((char*)hs + swz(w * 16 + li, ft * 32 + lg * 8, 256)) = hh;
    }
    __syncthreads();

    // ---- layer 2: out[e][f] = h @ W2^T (+b2) (*C) * vsrc[j]
    hv8 afrag[4];
#pragma unroll
    for (int kk = 0; kk < 4; ++kk)
        afrag[kk] = *(const hv8*)((const char*)hs + swz(w * 16 + li, kk * 64 + lg * 16, 256));

    const int ebase = e0 + w * 16 + lg * 4;
    int j4[4];
    float c4[4];
#pragma unroll
    for (int r = 0; r < 4; ++r) {
        j4[r] = jidx[ebase + r];
        if (ENV) c4[r] = 0.5f * __cosf(dist[ebase + r] * 0.31415926535897932f) + 0.5f;
    }

#pragma unroll
    for (int nt = 0; nt < 8; ++nt) {
        f32x4 acc = {0.f, 0.f, 0.f, 0.f};
#pragma unroll
        for (int kk = 0; kk < 4; ++kk)
            acc = __builtin_amdgcn_mfma_f32_16x16x32_f16(afrag[kk], W2f[(nt * 4 + kk) * 64 + l],
                                                         acc, 0, 0, 0);
        int f = nt * 16 + li;
        float b2v = b2[f];
#pragma unroll
        for (int r = 0; r < 4; ++r) {
            float res = (acc[r] + b2v) * vsrc[(long)j4[r] * 128 + f];
            if (ENV) res *= c4[r];
            __builtin_nontemporal_store(res, &out[(long)(ebase + r) * 128 + f]);
        }
    }
}

__global__ __launch_bounds__(256, 6) void edges_k(
        const float* __restrict__ dist_emb, const float* __restrict__ dist,
        const int* __restrict__ eidx, const hv8* __restrict__ W1f,
        const float* __restrict__ b1, const hv8* __restrict__ W2f,
        const float* __restrict__ b2, const float* __restrict__ v_,
        const float* __restrict__ fea_hull, const int* __restrict__ eidx_h,
        const hv8* __restrict__ Wh1f, const float* __restrict__ bh1,
        const hv8* __restrict__ Wh2f, const float* __restrict__ bh2,
        const float* __restrict__ v_hull, float* __restrict__ out) {
    __shared__ __align__(16) _Float16 embs[64 * 64];  // 8KB (rows 128B)
    __shared__ __align__(16) _Float16 hs[64 * 128];   // 16KB (rows 256B)
    int bid = blockIdx.x;
    if (bid < MAIN_BLOCKS) {
        edge_body<50, 64, true>(bid, dist_emb, dist, eidx, W1f, b1, W2f, b2, v_, out, embs, hs);
    } else {
        edge_body<16, 32, false>(bid - MAIN_BLOCKS, fea_hull, nullptr, eidx_h, Wh1f, bh1,
                                 Wh2f, bh2, v_hull, out + (long)EM * FDIM, embs, hs);
    }
}

extern "C" void kernel_launch(void* const* d_in, const int* in_sizes, int n_in,
                              void* d_out, int out_size, void* d_ws, size_t ws_size,
                              hipStream_t stream) {
    const float* v          = (const float*)d_in[0];
    const float* dist       = (const float*)d_in[1];
    const float* dist_emb   = (const float*)d_in[2];
    const float* fea_hull   = (const float*)d_in[3];
    const int*   eidx       = (const int*)d_in[4];   // row 0 = j
    const int*   eidx_h     = (const int*)d_in[5];
    const float* lin_w      = (const float*)d_in[6];
    const float* mlp1_w     = (const float*)d_in[7];
    const float* mlp1_b     = (const float*)d_in[8];
    const float* mlp2_w     = (const float*)d_in[9];
    const float* mlp2_b     = (const float*)d_in[10];
    const float* lin_hull_w = (const float*)d_in[11];
    const float* mlph1_w    = (const float*)d_in[12];
    const float* mlph1_b    = (const float*)d_in[13];
    const float* mlph2_w    = (const float*)d_in[14];
    const float* mlph2_b    = (const float*)d_in[15];

    float* ws      = (float*)d_ws;
    float* v_      = ws;               // 20000*128 f32
    float* v_hull  = v_ + NN * FDIM;   // 20000*128 f32
    _Float16* frag = (_Float16*)(v_hull + NN * FDIM);

    prep_k<<<(FRAG_TOTAL + 255) / 256, 256, 0, stream>>>(
        mlp1_w, mlp2_w, mlph1_w, mlph2_w, lin_w, lin_hull_w, frag);

    lin_mfma<<<(NN + 127) / 128, 512, 0, stream>>>(
        v, (const hv8*)(frag + OFF_LAF), (const hv8*)(frag + OFF_LBF), v_, v_hull);

    float* out = (float*)d_out;
    edges_k<<<MAIN_BLOCKS + HULL_BLOCKS, 256, 0, stream>>>(
        dist_emb, dist, eidx, (const hv8*)(frag + OFF_W1F), mlp1_b,
        (const hv8*)(frag + OFF_W2F), mlp2_b, v_,
        fea_hull, eidx_h, (const hv8*)(frag + OFF_WH1F), mlph1_b,
        (const hv8*)(frag + OFF_WH2F), mlph2_b, v_hull, out);
}

// Round 5
// 751.398 us; speedup vs baseline: 1.7646x; 1.0473x over previous
//
#include <hip/hip_runtime.h>
#include <math.h>

#define NN 20000
#define FDIM 128
#define EM 640000
#define EHULL 200000
#define MAIN_BLOCKS (EM / 64)    // 10000
#define HULL_BLOCKS (EHULL / 64) // 3125

typedef _Float16 hv2 __attribute__((ext_vector_type(2)));
typedef _Float16 hv4 __attribute__((ext_vector_type(4)));
typedef _Float16 hv8 __attribute__((ext_vector_type(8)));
typedef float f32x4 __attribute__((ext_vector_type(4)));

// fp16 fragment regions inside d_ws (element offsets, after 2 f32 node arrays)
#define OFF_W1F 0               // 16 fb  (mlp1_w,  C=50,  NK=2)
#define OFF_W2F 8192            // 32 fb  (mlp2_w,  C=128, NK=4)
#define OFF_WH1F 24576          // 8 fb   (mlph1_w, C=16,  NK=1)
#define OFF_WH2F 28672          // 32 fb  (mlph2_w, C=128, NK=4)
#define OFF_LAF 45056           // 32 fb  (lin_w,   C=128, NK=4)
#define OFF_LBF 61440           // 32 fb  (lin_hull_w)
#define FRAG_TOTAL 77824        // fp16 elements

__device__ __forceinline__ float ssp_f(float x) {
    float ax = fabsf(x);
    return fmaxf(x, 0.0f) + __logf(1.0f + __expf(-ax)) - 0.69314718055994531f;
}

// swizzled byte offset: row-major [row][rb bytes], XOR 16B-chunk swizzle
__device__ __forceinline__ int swz(int row, int colb, int rb) {
    return row * rb + (colb ^ ((row & 7) << 4));
}

__device__ __forceinline__ float2 ntload2(const float* p) {
    unsigned long long u = __builtin_nontemporal_load((const unsigned long long*)p);
    float2 r;
    __builtin_memcpy(&r, &u, 8);
    return r;
}

// ---------------------------------------------------------------------------
// Convert all weights to fp16 MFMA-fragment order:
//   dst[fb*512 + l*8 + j] = W[f*C + g], f = nt*16 + (l&15), g = kk*32 + (l>>4)*8 + j
// (identical layout serves A-frags (rows f, k=g) and B-frags (cols f, k=g))
// ---------------------------------------------------------------------------
__global__ __launch_bounds__(256) void prep_k(
        const float* __restrict__ mlp1_w, const float* __restrict__ mlp2_w,
        const float* __restrict__ mlph1_w, const float* __restrict__ mlph2_w,
        const float* __restrict__ lin_w, const float* __restrict__ lin_hull_w,
        _Float16* __restrict__ dst) {
    int i = blockIdx.x * 256 + threadIdx.x;
    if (i >= FRAG_TOTAL) return;
    int fbi = i >> 9, within = i & 511;
    int l = within >> 3, j = within & 7;
    const float* src;
    int C, NK, base;
    if (fbi < 16)       { src = mlp1_w;     C = 50;  NK = 2; base = 0; }
    else if (fbi < 48)  { src = mlp2_w;     C = 128; NK = 4; base = 16; }
    else if (fbi < 56)  { src = mlph1_w;    C = 16;  NK = 1; base = 48; }
    else if (fbi < 88)  { src = mlph2_w;    C = 128; NK = 4; base = 56; }
    else if (fbi < 120) { src = lin_w;      C = 128; NK = 4; base = 88; }
    else                { src = lin_hull_w; C = 128; NK = 4; base = 120; }
    int local = fbi - base;
    int nt = local / NK, kk = local % NK;
    int f = nt * 16 + (l & 15);
    int g = kk * 32 + (l >> 4) * 8 + j;
    float val = (g < C) ? src[f * C + g] : 0.0f;
    dst[i] = (_Float16)val;
}

// ---------------------------------------------------------------------------
// v_ = v @ lin_w^T and v_hull = v @ lin_hull_w^T.
// No LDS, no barrier: v fragments built in registers (B-role), weights as
// A-role frags from global (L1/L2-hot). Swapped product -> float4 stores.
// 64 nodes / block (4 waves x 16 nodes).
// ---------------------------------------------------------------------------
__global__ __launch_bounds__(256, 4) void lin_mfma2(
        const float* __restrict__ v, const hv8* __restrict__ LAf,
        const hv8* __restrict__ LBf, float* __restrict__ oA,
        float* __restrict__ oB) {
    const int t = threadIdx.x;
    const int w = t >> 6, l = t & 63, li = l & 15, lg = l >> 4;
    const int n = blockIdx.x * 64 + w * 16 + li;
    const bool ok = n < NN;
    const float* vrow = v + (long)(ok ? n : 0) * 128;

    hv8 bfrag[4];  // B-role: col = n (lane li), k = h
#pragma unroll
    for (int kk = 0; kk < 4; ++kk) {
        f32x4 x0 = *(const f32x4*)&vrow[kk * 32 + lg * 8];
        f32x4 x1 = *(const f32x4*)&vrow[kk * 32 + lg * 8 + 4];
        hv8 b = {(_Float16)x0[0], (_Float16)x0[1], (_Float16)x0[2], (_Float16)x0[3],
                 (_Float16)x1[0], (_Float16)x1[1], (_Float16)x1[2], (_Float16)x1[3]};
        bfrag[kk] = b;
    }

#pragma unroll
    for (int sel = 0; sel < 2; ++sel) {
        const hv8* A = sel ? LBf : LAf;
        float* o = sel ? oB : oA;
#pragma unroll
        for (int nt = 0; nt < 8; ++nt) {
            f32x4 acc = {0.f, 0.f, 0.f, 0.f};
#pragma unroll
            for (int kk = 0; kk < 4; ++kk)
                acc = __builtin_amdgcn_mfma_f32_16x16x32_f16(A[(nt * 4 + kk) * 64 + l],
                                                             bfrag[kk], acc, 0, 0, 0);
            // D[f][n]: f = nt*16 + lg*4 + r, n = lane li -> f32x4 store
            if (ok) *(f32x4*)&o[(long)n * 128 + nt * 16 + lg * 4] = acc;
        }
    }
}

// ---------------------------------------------------------------------------
// Fused edge MLP, 64 edges / 256 threads (4 waves x 16 edges).
// Both layers computed swapped (D[f][e]): lane owns ONE edge, 4 consecutive f
// per nt -> f32x4 gather of vsrc[j], f32x4 NT store of out.
// ---------------------------------------------------------------------------
template <int GDIM, int GPAD, bool ENV>
__device__ __forceinline__ void edge_body(
        int bid, const float* __restrict__ emb, const float* __restrict__ dist,
        const int* __restrict__ jidx, const hv8* __restrict__ W1f,
        const float* __restrict__ b1, const hv8* __restrict__ W2f,
        const float* __restrict__ b2, const float* __restrict__ vsrc,
        float* __restrict__ out, _Float16* embs /*[64 rows x 128B]*/,
        _Float16* hs /*[64 rows x 256B]*/) {
    constexpr int NK1 = GPAD / 32;
    constexpr int GP2 = GPAD / 2;

    const int t = threadIdx.x;
    const int e0 = bid * 64;

    // stage emb tile -> fp16 swizzled LDS (rows fixed at 128B stride)
    for (int i = t; i < 64 * GP2; i += 256) {
        int e = i / GP2, gp = i % GP2;
        float2 x = make_float2(0.f, 0.f);
        if (gp * 2 < GDIM) x = ntload2(&emb[(long)(e0 + e) * GDIM + gp * 2]);
        hv2 h = {(_Float16)x.x, (_Float16)x.y};
        *(hv2*)((char*)embs + swz(e, gp * 4, 128)) = h;
    }

    const int w = t >> 6, l = t & 63, li = l & 15, lg = l >> 4;
    const int e = e0 + w * 16 + li;  // this lane's edge
    // issue per-edge scalars early so they're resident by the epilogue
    const int j = jidx[e];
    float cenv = 1.0f;
    if (ENV) cenv = 0.5f * __cosf(dist[e] * 0.31415926535897932f) + 0.5f;

    __syncthreads();

    // ---- layer 1 (swapped): D[f][e] = W1 @ emb^T
    hv8 bfrag[NK1];
#pragma unroll
    for (int kk = 0; kk < NK1; ++kk)
        bfrag[kk] = *(const hv8*)((const char*)embs + swz(w * 16 + li, kk * 64 + lg * 16, 128));
#pragma unroll
    for (int ft = 0; ft < 8; ++ft) {
        f32x4 acc = {0.f, 0.f, 0.f, 0.f};
#pragma unroll
        for (int kk = 0; kk < NK1; ++kk)
            acc = __builtin_amdgcn_mfma_f32_16x16x32_f16(W1f[(ft * NK1 + kk) * 64 + l],
                                                         bfrag[kk], acc, 0, 0, 0);
        f32x4 bb = *(const f32x4*)&b1[ft * 16 + lg * 4];
        hv4 hh;
        hh[0] = (_Float16)ssp_f(acc[0] + bb[0]);
        hh[1] = (_Float16)ssp_f(acc[1] + bb[1]);
        hh[2] = (_Float16)ssp_f(acc[2] + bb[2]);
        hh[3] = (_Float16)ssp_f(acc[3] + bb[3]);
        *(hv4*)((char*)hs + swz(w * 16 + li, ft * 32 + lg * 8, 256)) = hh;
    }
    __syncthreads();

    // ---- layer 2 (swapped): D[f][e] = W2 @ h^T
    hv8 hfrag[4];
#pragma unroll
    for (int kk = 0; kk < 4; ++kk)
        hfrag[kk] = *(const hv8*)((const char*)hs + swz(w * 16 + li, kk * 64 + lg * 16, 256));

    const float* vrow = vsrc + (long)j * 128;
#pragma unroll
    for (int nt = 0; nt < 8; ++nt) {
        f32x4 acc = {0.f, 0.f, 0.f, 0.f};
#pragma unroll
        for (int kk = 0; kk < 4; ++kk)
            acc = __builtin_amdgcn_mfma_f32_16x16x32_f16(W2f[(nt * 4 + kk) * 64 + l],
                                                         hfrag[kk], acc, 0, 0, 0);
        f32x4 b2v = *(const f32x4*)&b2[nt * 16 + lg * 4];
        f32x4 vv = *(const f32x4*)&vrow[nt * 16 + lg * 4];
        f32x4 res = (acc + b2v) * vv;
        if (ENV) res *= cenv;
        __builtin_nontemporal_store(res, (f32x4*)&out[(long)e * 128 + nt * 16 + lg * 4]);
    }
}

__global__ __launch_bounds__(256, 4) void edges_k(
        const float* __restrict__ dist_emb, const float* __restrict__ dist,
        const int* __restrict__ eidx, const hv8* __restrict__ W1f,
        const float* __restrict__ b1, const hv8* __restrict__ W2f,
        const float* __restrict__ b2, const float* __restrict__ v_,
        const float* __restrict__ fea_hull, const int* __restrict__ eidx_h,
        const hv8* __restrict__ Wh1f, const float* __restrict__ bh1,
        const hv8* __restrict__ Wh2f, const float* __restrict__ bh2,
        const float* __restrict__ v_hull, float* __restrict__ out) {
    __shared__ __align__(16) _Float16 embs[64 * 64];  // 8KB (rows 128B)
    __shared__ __align__(16) _Float16 hs[64 * 128];   // 16KB (rows 256B)
    int bid = blockIdx.x;
    if (bid < MAIN_BLOCKS) {
        edge_body<50, 64, true>(bid, dist_emb, dist, eidx, W1f, b1, W2f, b2, v_, out, embs, hs);
    } else {
        edge_body<16, 32, false>(bid - MAIN_BLOCKS, fea_hull, nullptr, eidx_h, Wh1f, bh1,
                                 Wh2f, bh2, v_hull, out + (long)EM * FDIM, embs, hs);
    }
}

extern "C" void kernel_launch(void* const* d_in, const int* in_sizes, int n_in,
                              void* d_out, int out_size, void* d_ws, size_t ws_size,
                              hipStream_t stream) {
    const float* v          = (const float*)d_in[0];
    const float* dist       = (const float*)d_in[1];
    const float* dist_emb   = (const float*)d_in[2];
    const float* fea_hull   = (const float*)d_in[3];
    const int*   eidx       = (const int*)d_in[4];   // row 0 = j
    const int*   eidx_h     = (const int*)d_in[5];
    const float* lin_w      = (const float*)d_in[6];
    const float* mlp1_w     = (const float*)d_in[7];
    const float* mlp1_b     = (const float*)d_in[8];
    const float* mlp2_w     = (const float*)d_in[9];
    const float* mlp2_b     = (const float*)d_in[10];
    const float* lin_hull_w = (const float*)d_in[11];
    const float* mlph1_w    = (const float*)d_in[12];
    const float* mlph1_b    = (const float*)d_in[13];
    const float* mlph2_w    = (const float*)d_in[14];
    const float* mlph2_b    = (const float*)d_in[15];

    float* ws      = (float*)d_ws;
    float* v_      = ws;               // 20000*128 f32
    float* v_hull  = v_ + NN * FDIM;   // 20000*128 f32
    _Float16* frag = (_Float16*)(v_hull + NN * FDIM);

    prep_k<<<(FRAG_TOTAL + 255) / 256, 256, 0, stream>>>(
        mlp1_w, mlp2_w, mlph1_w, mlph2_w, lin_w, lin_hull_w, frag);

    lin_mfma2<<<(NN + 63) / 64, 256, 0, stream>>>(
        v, (const hv8*)(frag + OFF_LAF), (const hv8*)(frag + OFF_LBF), v_, v_hull);

    float* out = (float*)d_out;
    edges_k<<<MAIN_BLOCKS + HULL_BLOCKS, 256, 0, stream>>>(
        dist_emb, dist, eidx, (const hv8*)(frag + OFF_W1F), mlp1_b,
        (const hv8*)(frag + OFF_W2F), mlp2_b, v_,
        fea_hull, eidx_h, (const hv8*)(frag + OFF_WH1F), mlph1_b,
        (const hv8*)(frag + OFF_WH2F), mlph2_b, v_hull, out);
}

// Round 6
// 644.971 us; speedup vs baseline: 2.0558x; 1.1650x over previous
//
#include <hip/hip_runtime.h>
#include <math.h>

#define NN 20000
#define FDIM 128
#define EM 640000
#define EHULL 200000
#define MAIN_TILES (EM / 64)     // 10000
#define HULL_TILES (EHULL / 64)  // 3125
#define MAIN_BLKS 400
#define HULL_BLKS 112
#define MAIN_TPB 25              // 400*25 = 10000
#define HULL_TPB 28              // 112*28 = 3136 >= 3125

typedef _Float16 hv2 __attribute__((ext_vector_type(2)));
typedef _Float16 hv4 __attribute__((ext_vector_type(4)));
typedef _Float16 hv8 __attribute__((ext_vector_type(8)));
typedef float f32x2 __attribute__((ext_vector_type(2)));
typedef float f32x4 __attribute__((ext_vector_type(4)));

// fp16 fragment regions inside d_ws (element offsets, after 2 f32 node arrays)
#define OFF_W1F 0               // 16 fb  (mlp1_w,  C=50,  NK=2)
#define OFF_W2F 8192            // 32 fb  (mlp2_w,  C=128, NK=4)
#define OFF_WH1F 24576          // 8 fb   (mlph1_w, C=16,  NK=1)
#define OFF_WH2F 28672          // 32 fb  (mlph2_w, C=128, NK=4)
#define OFF_LAF 45056           // 32 fb  (lin_w,   C=128, NK=4)
#define OFF_LBF 61440           // 32 fb  (lin_hull_w) — contiguous after LAF
#define FRAG_TOTAL 77824        // fp16 elements

__device__ __forceinline__ float ssp_f(float x) {
    float ax = fabsf(x);
    return fmaxf(x, 0.0f) + __logf(1.0f + __expf(-ax)) - 0.69314718055994531f;
}

// swizzled byte offset: row-major [row][rb bytes], XOR 16B-chunk swizzle
__device__ __forceinline__ int swz(int row, int colb, int rb) {
    return row * rb + (colb ^ ((row & 7) << 4));
}

__device__ __forceinline__ f32x2 ntload2(const float* p) {
    return __builtin_nontemporal_load((const f32x2*)p);
}

// fragment fb, lane l from a fragment-linear fp16 array (global or LDS)
__device__ __forceinline__ hv8 ldfrag(const _Float16* s, int fb, int l) {
    return *(const hv8*)&s[(fb << 9) + (l << 3)];
}

// ---------------------------------------------------------------------------
// Convert all weights to fp16 MFMA-fragment order:
//   dst[fb*512 + l*8 + j] = W[f*C + g], f = nt*16 + (l&15), g = kk*32 + (l>>4)*8 + j
// ---------------------------------------------------------------------------
__global__ __launch_bounds__(256) void prep_k(
        const float* __restrict__ mlp1_w, const float* __restrict__ mlp2_w,
        const float* __restrict__ mlph1_w, const float* __restrict__ mlph2_w,
        const float* __restrict__ lin_w, const float* __restrict__ lin_hull_w,
        _Float16* __restrict__ dst) {
    int i = blockIdx.x * 256 + threadIdx.x;
    if (i >= FRAG_TOTAL) return;
    int fbi = i >> 9, within = i & 511;
    int l = within >> 3, j = within & 7;
    const float* src;
    int C, NK, base;
    if (fbi < 16)       { src = mlp1_w;     C = 50;  NK = 2; base = 0; }
    else if (fbi < 48)  { src = mlp2_w;     C = 128; NK = 4; base = 16; }
    else if (fbi < 56)  { src = mlph1_w;    C = 16;  NK = 1; base = 48; }
    else if (fbi < 88)  { src = mlph2_w;    C = 128; NK = 4; base = 56; }
    else if (fbi < 120) { src = lin_w;      C = 128; NK = 4; base = 88; }
    else                { src = lin_hull_w; C = 128; NK = 4; base = 120; }
    int local = fbi - base;
    int nt = local / NK, kk = local % NK;
    int f = nt * 16 + (l & 15);
    int g = kk * 32 + (l >> 4) * 8 + j;
    float val = (g < C) ? src[f * C + g] : 0.0f;
    dst[i] = (_Float16)val;
}

// ---------------------------------------------------------------------------
// lin: v_ = v @ lin_w^T, v_hull = v @ lin_hull_w^T. Weights staged to LDS
// (frag-linear, 64KB), v fragments built in registers. One 64-node tile/block.
// ---------------------------------------------------------------------------
__global__ __launch_bounds__(256) void lin_k3(
        const float* __restrict__ v, const _Float16* __restrict__ Lg,
        float* __restrict__ oA, float* __restrict__ oB) {
    __shared__ __align__(16) _Float16 Ws[2 * 32 * 512];  // 64KB: LA then LB
    const int t = threadIdx.x;
    for (int i = t * 8; i < 2 * 32 * 512; i += 2048)
        *(hv8*)&Ws[i] = *(const hv8*)&Lg[i];

    const int w = t >> 6, l = t & 63, li = l & 15, lg = l >> 4;
    const int n = blockIdx.x * 64 + w * 16 + li;
    const bool ok = n < NN;
    const float* vrow = v + (long)(ok ? n : 0) * 128;

    hv8 bfrag[4];  // B-role: col = n, k = h
#pragma unroll
    for (int kk = 0; kk < 4; ++kk) {
        f32x4 x0 = *(const f32x4*)&vrow[kk * 32 + lg * 8];
        f32x4 x1 = *(const f32x4*)&vrow[kk * 32 + lg * 8 + 4];
        hv8 b = {(_Float16)x0[0], (_Float16)x0[1], (_Float16)x0[2], (_Float16)x0[3],
                 (_Float16)x1[0], (_Float16)x1[1], (_Float16)x1[2], (_Float16)x1[3]};
        bfrag[kk] = b;
    }
    __syncthreads();

#pragma unroll
    for (int sel = 0; sel < 2; ++sel) {
        float* o = sel ? oB : oA;
        const _Float16* Wsel = Ws + sel * 16384;
#pragma unroll
        for (int nt = 0; nt < 8; ++nt) {
            f32x4 acc = {0.f, 0.f, 0.f, 0.f};
#pragma unroll
            for (int kk = 0; kk < 4; ++kk)
                acc = __builtin_amdgcn_mfma_f32_16x16x32_f16(ldfrag(Wsel, nt * 4 + kk, l),
                                                             bfrag[kk], acc, 0, 0, 0);
            if (ok) *(f32x4*)&o[(long)n * 128 + nt * 16 + lg * 4] = acc;
        }
    }
}

// ---------------------------------------------------------------------------
// Fused edge MLP over a contiguous range of 64-edge tiles per block.
// Weights LDS-stationary (frag-linear); emb double-buffered (issue-early /
// write-late); both layers swapped (D[f][e]); regular f32x4 out stores.
// ---------------------------------------------------------------------------
template <int GDIM, int GPAD, bool ENV>
__device__ __forceinline__ void edge_tiles(
        int tile0, int tend,
        const float* __restrict__ emb, const float* __restrict__ dist,
        const int* __restrict__ jidx,
        const _Float16* __restrict__ W1g, const float* __restrict__ b1,
        const _Float16* __restrict__ W2g, const float* __restrict__ b2,
        const float* __restrict__ vsrc, float* __restrict__ out,
        _Float16* W1s, _Float16* W2s, _Float16 (*embs)[64 * 64], _Float16* hs) {
    constexpr int NK1 = GPAD / 32;
    constexpr int GP2 = GPAD / 2;
    constexpr int NF1 = 8 * NK1;          // layer-1 fragment count
    constexpr int NST = 64 * GP2 / 256;   // stage iters per thread

    const int t = threadIdx.x;
    const int w = t >> 6, l = t & 63, li = l & 15, lg = l >> 4;

    // ---- stage weights once (coalesced 16B, linear LDS)
    for (int i = t * 8; i < NF1 * 512; i += 2048) *(hv8*)&W1s[i] = *(const hv8*)&W1g[i];
    for (int i = t * 8; i < 32 * 512; i += 2048) *(hv8*)&W2s[i] = *(const hv8*)&W2g[i];

    // ---- prologue: stage tile0 emb into buf 0
    {
        const int e0 = tile0 * 64;
#pragma unroll
        for (int s = 0; s < NST; ++s) {
            int i = s * 256 + t, e = i / GP2, gp = i % GP2;
            f32x2 x = {0.f, 0.f};
            if (gp * 2 < GDIM) x = ntload2(&emb[(long)(e0 + e) * GDIM + gp * 2]);
            hv2 h = {(_Float16)x[0], (_Float16)x[1]};
            *(hv2*)((char*)embs[0] + swz(e, gp * 4, 128)) = h;
        }
    }

    const int ntiles = tend - tile0;
    for (int ti = 0; ti < ntiles; ++ti) {
        const int e0 = (tile0 + ti) * 64;
        const int buf = ti & 1;
        const int elane = e0 + w * 16 + li;  // this lane's edge

        // issue next tile's stage loads early (regs only)
        f32x2 sreg[NST];
        const bool more = (ti + 1 < ntiles);  // block-uniform
        if (more) {
            const int en0 = e0 + 64;
#pragma unroll
            for (int s = 0; s < NST; ++s) {
                int i = s * 256 + t, e = i / GP2, gp = i % GP2;
                f32x2 x = {0.f, 0.f};
                if (gp * 2 < GDIM) x = ntload2(&emb[(long)(en0 + e) * GDIM + gp * 2]);
                sreg[s] = x;
            }
        }
        const int j = jidx[elane];
        float cenv = 1.0f;
        if (ENV) cenv = 0.5f * __cosf(dist[elane] * 0.31415926535897932f) + 0.5f;

        __syncthreads();  // embs[buf] ready; hs free (prev readers done)

        // ---- layer 1 (swapped): D[f][e] = W1 @ emb^T
        hv8 bfrag[NK1];
#pragma unroll
        for (int kk = 0; kk < NK1; ++kk)
            bfrag[kk] = *(const hv8*)((const char*)embs[buf] +
                                      swz(w * 16 + li, kk * 64 + lg * 16, 128));
#pragma unroll
        for (int ft = 0; ft < 8; ++ft) {
            f32x4 acc = {0.f, 0.f, 0.f, 0.f};
#pragma unroll
            for (int kk = 0; kk < NK1; ++kk)
                acc = __builtin_amdgcn_mfma_f32_16x16x32_f16(ldfrag(W1s, ft * NK1 + kk, l),
                                                             bfrag[kk], acc, 0, 0, 0);
            f32x4 bb = *(const f32x4*)&b1[ft * 16 + lg * 4];
            hv4 hh;
            hh[0] = (_Float16)ssp_f(acc[0] + bb[0]);
            hh[1] = (_Float16)ssp_f(acc[1] + bb[1]);
            hh[2] = (_Float16)ssp_f(acc[2] + bb[2]);
            hh[3] = (_Float16)ssp_f(acc[3] + bb[3]);
            *(hv4*)((char*)hs + swz(w * 16 + li, ft * 32 + lg * 8, 256)) = hh;
        }

        // write next tile's emb into the other buffer (T14 write-late)
        if (more) {
#pragma unroll
            for (int s = 0; s < NST; ++s) {
                int i = s * 256 + t, e = i / GP2, gp = i % GP2;
                hv2 h = {(_Float16)sreg[s][0], (_Float16)sreg[s][1]};
                *(hv2*)((char*)embs[buf ^ 1] + swz(e, gp * 4, 128)) = h;
            }
        }

        __syncthreads();  // hs ready

        // ---- layer 2 (swapped): D[f][e] = W2 @ h^T; epilogue fused
        hv8 hfrag[4];
#pragma unroll
        for (int kk = 0; kk < 4; ++kk)
            hfrag[kk] = *(const hv8*)((const char*)hs +
                                      swz(w * 16 + li, kk * 64 + lg * 16, 256));

        const float* vrow = vsrc + (long)j * 128;
#pragma unroll
        for (int nt = 0; nt < 8; ++nt) {
            f32x4 acc = {0.f, 0.f, 0.f, 0.f};
#pragma unroll
            for (int kk = 0; kk < 4; ++kk)
                acc = __builtin_amdgcn_mfma_f32_16x16x32_f16(ldfrag(W2s, nt * 4 + kk, l),
                                                             hfrag[kk], acc, 0, 0, 0);
            f32x4 b2v = *(const f32x4*)&b2[nt * 16 + lg * 4];
            f32x4 vv = *(const f32x4*)&vrow[nt * 16 + lg * 4];
            f32x4 res = (acc + b2v) * vv;
            if (ENV) res *= cenv;
            *(f32x4*)&out[(long)elane * 128 + nt * 16 + lg * 4] = res;  // L2-merged full lines
        }
    }
}

__global__ __launch_bounds__(256) void edges_k2(
        const float* __restrict__ dist_emb, const float* __restrict__ dist,
        const int* __restrict__ eidx, const float* __restrict__ fea_hull,
        const int* __restrict__ eidx_h, const _Float16* __restrict__ frag,
        const float* __restrict__ b1, const float* __restrict__ b2,
        const float* __restrict__ bh1, const float* __restrict__ bh2,
        const float* __restrict__ v_, const float* __restrict__ v_hull,
        float* __restrict__ out) {
    __shared__ __align__(16) _Float16 W1s[16 * 512];     // 16KB
    __shared__ __align__(16) _Float16 W2s[32 * 512];     // 32KB
    __shared__ __align__(16) _Float16 embs[2][64 * 64];  // 16KB dbuf
    __shared__ __align__(16) _Float16 hs[64 * 128];      // 16KB
    const int b = blockIdx.x;
    if (b < MAIN_BLKS) {
        const int t0 = b * MAIN_TPB;
        edge_tiles<50, 64, true>(t0, t0 + MAIN_TPB, dist_emb, dist, eidx,
                                 frag + OFF_W1F, b1, frag + OFF_W2F, b2, v_, out,
                                 W1s, W2s, embs, hs);
    } else {
        const int hb = b - MAIN_BLKS;
        const int t0 = hb * HULL_TPB;
        const int t1 = (t0 + HULL_TPB < HULL_TILES) ? t0 + HULL_TPB : HULL_TILES;
        edge_tiles<16, 32, false>(t0, t1, fea_hull, nullptr, eidx_h,
                                  frag + OFF_WH1F, bh1, frag + OFF_WH2F, bh2, v_hull,
                                  out + (long)EM * FDIM, W1s, W2s, embs, hs);
    }
}

extern "C" void kernel_launch(void* const* d_in, const int* in_sizes, int n_in,
                              void* d_out, int out_size, void* d_ws, size_t ws_size,
                              hipStream_t stream) {
    const float* v          = (const float*)d_in[0];
    const float* dist       = (const float*)d_in[1];
    const float* dist_emb   = (const float*)d_in[2];
    const float* fea_hull   = (const float*)d_in[3];
    const int*   eidx       = (const int*)d_in[4];   // row 0 = j
    const int*   eidx_h     = (const int*)d_in[5];
    const float* lin_w      = (const float*)d_in[6];
    const float* mlp1_w     = (const float*)d_in[7];
    const float* mlp1_b     = (const float*)d_in[8];
    const float* mlp2_w     = (const float*)d_in[9];
    const float* mlp2_b     = (const float*)d_in[10];
    const float* lin_hull_w = (const float*)d_in[11];
    const float* mlph1_w    = (const float*)d_in[12];
    const float* mlph1_b    = (const float*)d_in[13];
    const float* mlph2_w    = (const float*)d_in[14];
    const float* mlph2_b    = (const float*)d_in[15];

    float* ws      = (float*)d_ws;
    float* v_      = ws;               // 20000*128 f32
    float* v_hull  = v_ + NN * FDIM;   // 20000*128 f32
    _Float16* frag = (_Float16*)(v_hull + NN * FDIM);

    prep_k<<<(FRAG_TOTAL + 255) / 256, 256, 0, stream>>>(
        mlp1_w, mlp2_w, mlph1_w, mlph2_w, lin_w, lin_hull_w, frag);

    lin_k3<<<(NN + 63) / 64, 256, 0, stream>>>(v, frag + OFF_LAF, v_, v_hull);

    float* out = (float*)d_out;
    edges_k2<<<MAIN_BLKS + HULL_BLKS, 256, 0, stream>>>(
        dist_emb, dist, eidx, fea_hull, eidx_h, frag,
        mlp1_b, mlp2_b, mlph1_b, mlph2_b, v_, v_hull, out);
}